// Round 20
// baseline (277.598 us; speedup 1.0000x reference)
//
#include <hip/hip_runtime.h>
#include <cstdio>
#include <cstdint>

// Problem constants
#define B_    16
#define N_    577
#define C_    768
#define H_    12
#define D_    64
#define KKEEP 288            // max(1, int(576*0.5))
#define SCALE 0.125f         // 64^-0.5 (exact power of 2)
#define LOG2E 1.4426950408889634f
#define M_TOT (B_ * N_)      // 9232
#define NKT   24             // K tiles (768/32)
#define PLROW ((size_t)N_ * 64)       // q/k plane bh stride (ushorts)

typedef __bf16 bf16x8_t __attribute__((ext_vector_type(8)));
typedef __bf16 bf16x4_t __attribute__((ext_vector_type(4)));
typedef float  f32x4_t  __attribute__((ext_vector_type(4)));
typedef unsigned int u32x4_t __attribute__((ext_vector_type(4)));
typedef unsigned int u32x2_t __attribute__((ext_vector_type(2)));

__device__ __forceinline__ f32x4_t mfma_bf16(bf16x8_t a, bf16x8_t b, f32x4_t c) {
    return __builtin_amdgcn_mfma_f32_16x16x32_bf16(a, b, c, 0, 0, 0);
}

// async global->LDS, 16B per lane (lds dest = wave-uniform base + lane*16)
__device__ __forceinline__ void gload16(const ushort* g, ushort* l) {
    __builtin_amdgcn_global_load_lds(
        (const __attribute__((address_space(1))) void*)g,
        (__attribute__((address_space(3))) void*)l, 16, 0, 0);
}
#define VMCNT(n) asm volatile("s_waitcnt vmcnt(" #n ")" ::: "memory")
#define LGKM0()  asm volatile("s_waitcnt lgkmcnt(0)" ::: "memory")
#define SB() __builtin_amdgcn_sched_barrier(0)

// bijective XCD-aware block remap (m204)
__device__ __forceinline__ int xcd_swz(int bid, int nwg) {
    int q = nwg >> 3, r = nwg & 7;
    int xcd = bid & 7, off = bid >> 3;
    int base = (xcd < r) ? xcd * (q + 1) : r * (q + 1) + (xcd - r) * q;
    return base + off;
}

// RTZ split of f32 into two bf16 bit patterns (x ~= hi + lo, err ~2^-16 |x|)
__device__ __forceinline__ void splitf(float x, unsigned int &hi, unsigned int &lo) {
    unsigned int u = __float_as_uint(x);
    hi = u >> 16;
    float r = x - __uint_as_float(u & 0xffff0000u);
    lo = __float_as_uint(r) >> 16;
}
__device__ __forceinline__ unsigned int bf16rne(float x) {
    unsigned int u = __float_as_uint(x);
    return (u + 0x7fffu + ((u >> 16) & 1u)) >> 16;
}

// ---------------------------------------------------------------------------
// Pack one 128x32 tile of f32 [nrows x 768] into split hi/lo bf16 planes,
// pre-swizzled to the fragT layout.
// ---------------------------------------------------------------------------
__device__ __forceinline__ void pack_tile(const float* __restrict__ src,
                                          ushort* __restrict__ dH,
                                          ushort* __restrict__ dL,
                                          int nrows, int tile) {
    int kt = tile % NKT, mt = tile / NKT;
    int w = threadIdx.x;
    int row = w >> 1, h = w & 1;
    int m = mt * 128 + row;
    int sw = (row >> 1) & 3;
    float f[16];
    if (m < nrows) {
        const float* s = src + (size_t)m * C_ + kt * 32;
        int sa = (2 * h) ^ sw, sb = (2 * h + 1) ^ sw;
        *(float4*)&f[0]  = *(const float4*)(s + sa * 8);
        *(float4*)&f[4]  = *(const float4*)(s + sa * 8 + 4);
        *(float4*)&f[8]  = *(const float4*)(s + sb * 8);
        *(float4*)&f[12] = *(const float4*)(s + sb * 8 + 4);
    } else {
#pragma unroll
        for (int i = 0; i < 16; i++) f[i] = 0.f;
    }
    unsigned hi[16], lo[16];
#pragma unroll
    for (int i = 0; i < 16; i++) splitf(f[i], hi[i], lo[i]);
    u32x4_t h0 = {hi[0] | (hi[1] << 16), hi[2] | (hi[3] << 16),
                  hi[4] | (hi[5] << 16), hi[6] | (hi[7] << 16)};
    u32x4_t h1 = {hi[8] | (hi[9] << 16), hi[10] | (hi[11] << 16),
                  hi[12] | (hi[13] << 16), hi[14] | (hi[15] << 16)};
    u32x4_t l0 = {lo[0] | (lo[1] << 16), lo[2] | (lo[3] << 16),
                  lo[4] | (lo[5] << 16), lo[6] | (lo[7] << 16)};
    u32x4_t l1 = {lo[8] | (lo[9] << 16), lo[10] | (lo[11] << 16),
                  lo[12] | (lo[13] << 16), lo[14] | (lo[15] << 16)};
    size_t dbase = (size_t)tile * 4096 + row * 32;
    *(u32x4_t*)&dH[dbase + (2 * h) * 8]     = h0;
    *(u32x4_t*)&dH[dbase + (2 * h + 1) * 8] = h1;
    *(u32x4_t*)&dL[dbase + (2 * h) * 8]     = l0;
    *(u32x4_t*)&dL[dbase + (2 * h + 1) * 8] = l1;
}

// Pack one 128x32 tile, single bf16 plane (RNE), pre-swizzled.
__device__ __forceinline__ void pack_tile_rne(const float* __restrict__ src,
                                              ushort* __restrict__ dst,
                                              int nrows, int tile) {
    int kt = tile % NKT, mt = tile / NKT;
    int w = threadIdx.x;
    int row = w >> 1, h = w & 1;
    int m = mt * 128 + row;
    int sw = (row >> 1) & 3;
    float f[16];
    if (m < nrows) {
        const float* s = src + (size_t)m * C_ + kt * 32;
        int sa = (2 * h) ^ sw, sb = (2 * h + 1) ^ sw;
        *(float4*)&f[0]  = *(const float4*)(s + sa * 8);
        *(float4*)&f[4]  = *(const float4*)(s + sa * 8 + 4);
        *(float4*)&f[8]  = *(const float4*)(s + sb * 8);
        *(float4*)&f[12] = *(const float4*)(s + sb * 8 + 4);
    } else {
#pragma unroll
        for (int i = 0; i < 16; i++) f[i] = 0.f;
    }
    unsigned hi[16];
#pragma unroll
    for (int i = 0; i < 16; i++) hi[i] = bf16rne(f[i]);
    u32x4_t h0 = {hi[0] | (hi[1] << 16), hi[2] | (hi[3] << 16),
                  hi[4] | (hi[5] << 16), hi[6] | (hi[7] << 16)};
    u32x4_t h1 = {hi[8] | (hi[9] << 16), hi[10] | (hi[11] << 16),
                  hi[12] | (hi[13] << 16), hi[14] | (hi[15] << 16)};
    size_t dbase = (size_t)tile * 4096 + row * 32;
    *(u32x4_t*)&dst[dbase + (2 * h) * 8]     = h0;
    *(u32x4_t*)&dst[dbase + (2 * h + 1) * 8] = h1;
}

#define NXP 1752              // 73*24 X tiles
#define NWP 432               // 18*24 W tiles
#define NPJ 144               // 6*24 Wproj tiles
#define NZ  37                // ceil(9232/256)

// ---------------------------------------------------------------------------
// Merged prepass: X pack | Wqkv pack | Wproj tiled RNE | kvmask zero
// ---------------------------------------------------------------------------
__global__ __launch_bounds__(256) void pack_all_kernel(const float* __restrict__ x,
                                                       const float* __restrict__ Wqkv,
                                                       const float* __restrict__ Wproj,
                                                       ushort* __restrict__ XplH,
                                                       ushort* __restrict__ XplL,
                                                       ushort* __restrict__ WplH,
                                                       ushort* __restrict__ WplL,
                                                       ushort* __restrict__ Wpjb,
                                                       float* __restrict__ kvmask) {
    int bid = blockIdx.x;
    if (bid < NXP) {
        pack_tile(x, XplH, XplL, M_TOT, bid);
    } else if (bid < NXP + NWP) {
        pack_tile(Wqkv, WplH, WplL, 3 * C_, bid - NXP);
    } else if (bid < NXP + NWP + NPJ) {
        pack_tile_rne(Wproj, Wpjb, C_, bid - NXP - NWP);
    } else {
        int i = (bid - NXP - NWP - NPJ) * 256 + threadIdx.x;
        if (i < B_ * N_) kvmask[i] = 0.f;
    }
}

// ===========================================================================
// 64x64 bf16 LDS tiles: 64 ushort/row, 8 slots of 8; phys slot = logical^(row&7)
// ===========================================================================
__device__ __forceinline__ bf16x8_t fragT(const ushort* H, int row, int c, int ls) {
    int phys = ((c << 2) + ls) ^ (row & 7);
    return __builtin_bit_cast(bf16x8_t, *(const u32x4_t*)&H[(row << 6) + (phys << 3)]);
}

// ---------------------------------------------------------------------------
// Merged MFMA GEMM 1: qkv = x @ Wqkv^T, 18x73 tile grid.
// A planes double-buffered (counted), B planes single-buffered (issue-early)
// -> 48KB LDS -> 3 blocks/CU.
// ---------------------------------------------------------------------------
__global__ __launch_bounds__(256) void gemm_qkv_mfma(const ushort* __restrict__ XplH,
                                                     const ushort* __restrict__ XplL,
                                                     const ushort* __restrict__ WplH,
                                                     const ushort* __restrict__ WplL,
                                                     ushort* __restrict__ qhp,
                                                     ushort* __restrict__ qlp,
                                                     ushort* __restrict__ khp,
                                                     ushort* __restrict__ klp,
                                                     ushort* __restrict__ vtp) {
    __shared__ ushort SMEM[24576];     // 48KB
    ushort* Ah = SMEM;                 // [2][4096]
    ushort* Al = SMEM + 8192;          // [2][4096]
    ushort* Bh = SMEM + 16384;         // [4096] single
    ushort* Bl = SMEM + 20480;         // [4096] single
    const int bid = xcd_swz(blockIdx.x, 18 * 73);
    const int bx = bid % 18, by = bid / 18;
    const int tid = threadIdx.x;
    const int lane = tid & 63, wave = tid >> 6;
    const int wr = wave >> 1, wc = wave & 1;
    const int lr = lane & 15, ls = lane >> 4;
    const int m0 = by * 128;
    const int o0 = wave * 1024, o1 = o0 + 512;
    const int la = lane * 8;
    const size_t abase = (size_t)by * NKT * 4096;
    const size_t bbase = (size_t)bx * NKT * 4096;
    f32x4_t acc[4][4] = {};

    if (bx < 12) {
        // ---------------- q/k path: 3-term split ----------------
        auto stageA = [&](int buf, int kt) {
            const size_t ta = abase + (size_t)kt * 4096;
            gload16(XplH + ta + o0 + la, &Ah[buf * 4096 + o0]);
            gload16(XplH + ta + o1 + la, &Ah[buf * 4096 + o1]);
            gload16(XplL + ta + o0 + la, &Al[buf * 4096 + o0]);
            gload16(XplL + ta + o1 + la, &Al[buf * 4096 + o1]);
        };
        auto stageB = [&](int kt) {
            const size_t tb = bbase + (size_t)kt * 4096;
            gload16(WplH + tb + o0 + la, &Bh[o0]);
            gload16(WplH + tb + o1 + la, &Bh[o1]);
            gload16(WplL + tb + o0 + la, &Bl[o0]);
            gload16(WplL + tb + o1 + la, &Bl[o1]);
        };
        stageA(0, 0);
        stageB(0);
        VMCNT(0);
        SB(); __builtin_amdgcn_s_barrier(); SB();
#pragma unroll 1
        for (int kt = 0; kt < NKT; ++kt) {
            const int cur = kt & 1;
            if (kt + 1 < NKT) stageA(cur ^ 1, kt + 1);   // other buf, safe now
            bf16x8_t fah[4], fal[4], fbh[4], fbl[4];
#pragma unroll
            for (int i = 0; i < 4; i++) {
                int rowA = wr * 64 + i * 16 + lr;
                int pa = ls ^ ((rowA >> 1) & 3);
                fah[i] = __builtin_bit_cast(bf16x8_t, *(const u32x4_t*)&Ah[cur * 4096 + rowA * 32 + pa * 8]);
                fal[i] = __builtin_bit_cast(bf16x8_t, *(const u32x4_t*)&Al[cur * 4096 + rowA * 32 + pa * 8]);
                int rowB = wc * 64 + i * 16 + lr;
                int pb = ls ^ ((rowB >> 1) & 3);
                fbh[i] = __builtin_bit_cast(bf16x8_t, *(const u32x4_t*)&Bh[rowB * 32 + pb * 8]);
                fbl[i] = __builtin_bit_cast(bf16x8_t, *(const u32x4_t*)&Bl[rowB * 32 + pb * 8]);
            }
            LGKM0(); SB();
            __builtin_amdgcn_s_barrier();   // B frag reads retired block-wide
            SB();
            if (kt + 1 < NKT) stageB(kt + 1);  // overwrite single B buf (async)
            __builtin_amdgcn_s_setprio(1);
#pragma unroll
            for (int i = 0; i < 4; i++)
#pragma unroll
                for (int j = 0; j < 4; j++) {
                    acc[i][j] = mfma_bf16(fah[i], fbh[j], acc[i][j]);
                    acc[i][j] = mfma_bf16(fah[i], fbl[j], acc[i][j]);
                    acc[i][j] = mfma_bf16(fal[i], fbh[j], acc[i][j]);
                }
            __builtin_amdgcn_s_setprio(0);
            if (kt + 1 < NKT) {
                VMCNT(0); SB();
                __builtin_amdgcn_s_barrier();   // A(t+1), B(t+1) ready
                SB();
            }
        }
        // coalesced epilogue: two half-tile u32 bounce rounds (32KB each)
        const int n0 = bx * 128;
        const int s = n0 / C_;
        __syncthreads();
        unsigned* T = (unsigned*)SMEM;   // 64 x 128 u32 = 32KB
        const float sc = (s == 0) ? SCALE * LOG2E : 1.0f;
        ushort* dh = (s == 1) ? khp : qhp;
        ushort* dl = (s == 1) ? klp : qlp;
        const int hh0 = (n0 % C_) / D_;
#pragma unroll 1
        for (int round = 0; round < 2; ++round) {
            if (wr == round) {
#pragma unroll
                for (int j = 0; j < 4; j++) {
                    int nl = wc * 64 + j * 16 + lr;
#pragma unroll
                    for (int i = 0; i < 4; i++) {
#pragma unroll
                        for (int r = 0; r < 4; r++) {
                            int ml = wr * 64 + i * 16 + ls * 4 + r;   // full row id
                            unsigned hi, lo;
                            splitf(acc[i][j][r] * sc, hi, lo);
                            int idx = (ml & 63) * 128 +
                                      ((((nl >> 3) ^ ((ml >> 2) & 7)) << 3) | (nl & 7));
                            T[idx] = hi | (lo << 16);
                        }
                    }
                }
            }
            __syncthreads();
#pragma unroll
            for (int it = 0; it < 4; ++it) {
                int g = it * 256 + tid;          // 1024 slots = 64 rows x 16
                int sl = g & 7;
                int m_local64 = (g >> 3) & 63;
                int hh_half = g >> 9;            // 0 or 1
                int m_local = round * 64 + m_local64;
                int m = m0 + m_local;
                if (m < M_TOT) {
                    int b = m / N_, n = m % N_;
                    int dg = sl ^ (n & 7);
                    int grp = (hh_half * 8 + dg) ^ ((m_local >> 2) & 7);
                    const unsigned* src = &T[m_local64 * 128 + grp * 8];
                    u32x4_t a = *(const u32x4_t*)src;
                    u32x4_t bvv = *(const u32x4_t*)(src + 4);
                    u32x4_t hiv = {(a[0] & 0xffffu) | (a[1] << 16),
                                   (a[2] & 0xffffu) | (a[3] << 16),
                                   (bvv[0] & 0xffffu) | (bvv[1] << 16),
                                   (bvv[2] & 0xffffu) | (bvv[3] << 16)};
                    u32x4_t lov = {(a[0] >> 16) | (a[1] & 0xffff0000u),
                                   (a[2] >> 16) | (a[3] & 0xffff0000u),
                                   (bvv[0] >> 16) | (bvv[1] & 0xffff0000u),
                                   (bvv[2] >> 16) | (bvv[3] & 0xffff0000u)};
                    size_t off = (size_t)(b * H_ + hh0 + hh_half) * PLROW + (size_t)n * 64 + sl * 8;
                    *(u32x4_t*)&dh[off] = hiv;
                    *(u32x4_t*)&dl[off] = lov;
                }
            }
            if (round == 0) __syncthreads();
        }
    } else {
        // ---------------- v path: 2-term split ----------------
        auto stageA = [&](int buf, int kt) {
            const size_t ta = abase + (size_t)kt * 4096;
            gload16(XplH + ta + o0 + la, &Ah[buf * 4096 + o0]);
            gload16(XplH + ta + o1 + la, &Ah[buf * 4096 + o1]);
            gload16(XplL + ta + o0 + la, &Al[buf * 4096 + o0]);
            gload16(XplL + ta + o1 + la, &Al[buf * 4096 + o1]);
        };
        auto stageB = [&](int kt) {
            const size_t tb = bbase + (size_t)kt * 4096;
            gload16(WplH + tb + o0 + la, &Bh[o0]);
            gload16(WplH + tb + o1 + la, &Bh[o1]);
        };
        stageA(0, 0);
        stageB(0);
        VMCNT(0);
        SB(); __builtin_amdgcn_s_barrier(); SB();
#pragma unroll 1
        for (int kt = 0; kt < NKT; ++kt) {
            const int cur = kt & 1;
            if (kt + 1 < NKT) stageA(cur ^ 1, kt + 1);
            bf16x8_t fah[4], fal[4], fbh[4];
#pragma unroll
            for (int i = 0; i < 4; i++) {
                int rowA = wr * 64 + i * 16 + lr;
                int pa = ls ^ ((rowA >> 1) & 3);
                fah[i] = __builtin_bit_cast(bf16x8_t, *(const u32x4_t*)&Ah[cur * 4096 + rowA * 32 + pa * 8]);
                fal[i] = __builtin_bit_cast(bf16x8_t, *(const u32x4_t*)&Al[cur * 4096 + rowA * 32 + pa * 8]);
                int rowB = wc * 64 + i * 16 + lr;
                int pb = ls ^ ((rowB >> 1) & 3);
                fbh[i] = __builtin_bit_cast(bf16x8_t, *(const u32x4_t*)&Bh[rowB * 32 + pb * 8]);
            }
            LGKM0(); SB();
            __builtin_amdgcn_s_barrier();
            SB();
            if (kt + 1 < NKT) stageB(kt + 1);
            __builtin_amdgcn_s_setprio(1);
#pragma unroll
            for (int i = 0; i < 4; i++)
#pragma unroll
                for (int j = 0; j < 4; j++) {
                    acc[i][j] = mfma_bf16(fah[i], fbh[j], acc[i][j]);
                    acc[i][j] = mfma_bf16(fal[i], fbh[j], acc[i][j]);
                }
            __builtin_amdgcn_s_setprio(0);
            if (kt + 1 < NKT) {
                VMCNT(0); SB();
                __builtin_amdgcn_s_barrier();
                SB();
            }
        }
        const int n0v = (bx - 12) * 128;
#pragma unroll
        for (int j = 0; j < 4; j++) {
            int ng = n0v + wc * 64 + j * 16 + lr;
            int hh = ng / D_;
            int d = ng % D_;
#pragma unroll
            for (int i = 0; i < 4; i++) {
                int mg0 = m0 + wr * 64 + i * 16 + ls * 4;
#pragma unroll
                for (int r = 0; r < 4; r++) {
                    int m = mg0 + r;
                    if (m < M_TOT) {
                        int b = m / N_, n = m % N_;
                        int jt = n >> 6, jl = n & 63;
                        size_t off = ((size_t)(b * H_ + hh) * 10 + jt) * 4096 +
                                     (size_t)d * 64 + (((jl >> 3) ^ (d & 7)) << 3) + (jl & 7);
                        vtp[off] = __builtin_bit_cast(unsigned short, (__bf16)acc[i][j][r]);
                    }
                }
            }
        }
    }
}

// ---------------------------------------------------------------------------
// Fused Pass R+CS: per (bh, 128-q tile):
//  pass A: rowsum over all j (3-term S), w = 1/rowsum in LDS (padding q -> 0).
//  pass B: re-stream K, same 3-term S, colsum partials per j via 16-lane
//          butterfly; write colsum_part[qt][bh][j].
// ---------------------------------------------------------------------------
__global__ __launch_bounds__(512) void attn_rc_mfma(const ushort* __restrict__ qh,
                                                    const ushort* __restrict__ ql,
                                                    const ushort* __restrict__ kh,
                                                    const ushort* __restrict__ kl,
                                                    float* __restrict__ colsum_part) {
    __shared__ ushort Qh[8192], Ql[8192];
    __shared__ ushort Kh[4096], Kl[4096];
    __shared__ float red[8][64];
    __shared__ float wsld[128];
    __shared__ float cpart[2][64];
    const int bid = xcd_swz(blockIdx.x, 5 * B_ * H_);
    const int bh = bid / 5, qt5 = bid % 5, q0 = qt5 * 128;
    const int tid = threadIdx.x, lane = tid & 63, wv = tid >> 6;
    const int wg = wv >> 2, wl = wv & 3;
    const int lr = lane & 15, ls = lane >> 4;
    const size_t bho = (size_t)bh * PLROW;
    const ushort* qhp = qh + bho; const ushort* qlp = ql + bho;
    const ushort* khp = kh + bho; const ushort* klp = kl + bho;
    auto qrow = [&](int rr) { return (size_t)min(q0 + wv * 16 + rr * 8 + (lane >> 3), N_ - 1) * 64 + (lane & 7) * 8; };
    gload16(qhp + qrow(0), &Qh[wv * 1024]);
    gload16(qhp + qrow(1), &Qh[wv * 1024 + 512]);
    gload16(qlp + qrow(0), &Ql[wv * 1024]);
    gload16(qlp + qrow(1), &Ql[wv * 1024 + 512]);
    auto krow = [&](int j0) { return (size_t)min(j0 + wv * 8 + (lane >> 3), N_ - 1) * 64 + (lane & 7) * 8; };
    auto stageK = [&](int j0) {
        gload16(khp + krow(j0), &Kh[wv * 512]);
        gload16(klp + krow(j0), &Kl[wv * 512]);
    };
    stageK(0);
    VMCNT(0);
    __syncthreads();
    bf16x8_t fqh[4][2], fql[4][2];
#pragma unroll
    for (int i = 0; i < 4; i++)
#pragma unroll
        for (int c = 0; c < 2; c++) {
            fqh[i][c] = fragT(Qh, wg * 64 + i * 16 + lr, c, ls);
            fql[i][c] = fragT(Ql, wg * 64 + i * 16 + lr, c, ls);
        }
    // ---------------- pass A: rowsum ----------------
    float rs[4] = {0.f, 0.f, 0.f, 0.f};
#pragma unroll 1
    for (int t = 0; t < 10; ++t) {
        bf16x8_t fkh[2], fkl[2];
#pragma unroll
        for (int c = 0; c < 2; c++) {
            fkh[c] = fragT(Kh, wl * 16 + lr, c, ls);
            fkl[c] = fragT(Kl, wl * 16 + lr, c, ls);
        }
        LGKM0(); SB();
        __builtin_amdgcn_s_barrier();
        SB();
        if (t < 9) stageK((t + 1) * 64);
        int jbase = t * 64 + wl * 16 + ls * 4;
#pragma unroll
        for (int i = 0; i < 4; i++) {
            f32x4_t s = {0.f, 0.f, 0.f, 0.f};
            __builtin_amdgcn_s_setprio(1);
#pragma unroll
            for (int c = 0; c < 2; c++) {
                s = mfma_bf16(fkh[c], fqh[i][c], s);
                s = mfma_bf16(fkh[c], fql[i][c], s);
                s = mfma_bf16(fkl[c], fqh[i][c], s);
            }
            __builtin_amdgcn_s_setprio(0);
#pragma unroll
            for (int r = 0; r < 4; r++)
                rs[i] += (jbase + r < N_) ? __builtin_amdgcn_exp2f(s[r]) : 0.f;
        }
        if (t < 9) {
            VMCNT(0); SB();
            __builtin_amdgcn_s_barrier();
            SB();
        }
    }
#pragma unroll
    for (int i = 0; i < 4; i++) {
        float v2 = rs[i];
        v2 += __shfl_xor(v2, 16);
        v2 += __shfl_xor(v2, 32);
        if (ls == 0) red[wv][i * 16 + lr] = v2;
    }
    __syncthreads();
    if (tid < 128) {
        int grp = tid >> 6, qlc = tid & 63;
        float s = red[grp * 4 + 0][qlc] + red[grp * 4 + 1][qlc] +
                  red[grp * 4 + 2][qlc] + red[grp * 4 + 3][qlc];
        // CRITICAL: padding q rows (clamped duplicates of row 576) must
        // contribute 0 in pass B — match the old wsAll zero-fill semantics.
        wsld[grp * 64 + qlc] = (q0 + grp * 64 + qlc < N_) ? 1.0f / s : 0.f;
    }
    __syncthreads();        // wsld visible; pass-A K reads long retired
    // ---------------- pass B: colsum partials ----------------
    float wq[4];
#pragma unroll
    for (int i = 0; i < 4; i++) wq[i] = wsld[wg * 64 + i * 16 + lr];
    stageK(0);
    VMCNT(0);
    SB(); __builtin_amdgcn_s_barrier(); SB();
    float* cpout = colsum_part + ((size_t)qt5 * (B_ * H_) + bh) * N_;
#pragma unroll 1
    for (int t = 0; t < 10; ++t) {
        bf16x8_t fkh[2], fkl[2];
#pragma unroll
        for (int c = 0; c < 2; c++) {
            fkh[c] = fragT(Kh, wl * 16 + lr, c, ls);
            fkl[c] = fragT(Kl, wl * 16 + lr, c, ls);
        }
        LGKM0(); SB();
        __builtin_amdgcn_s_barrier();   // K frag reads retired block-wide
        SB();
        if (t < 9) stageK((t + 1) * 64);
        float cj[4] = {0.f, 0.f, 0.f, 0.f};
#pragma unroll
        for (int i = 0; i < 4; i++) {
            f32x4_t s = {0.f, 0.f, 0.f, 0.f};
            __builtin_amdgcn_s_setprio(1);
#pragma unroll
            for (int c = 0; c < 2; c++) {
                s = mfma_bf16(fkh[c], fqh[i][c], s);
                s = mfma_bf16(fkh[c], fql[i][c], s);
                s = mfma_bf16(fkl[c], fqh[i][c], s);
            }
            __builtin_amdgcn_s_setprio(0);
#pragma unroll
            for (int r = 0; r < 4; r++)
                cj[r] += __builtin_amdgcn_exp2f(s[r]) * wq[i];
        }
        // butterfly over the 16-lane lr group: every lane gets sum over 16 q's
#pragma unroll
        for (int r = 0; r < 4; r++) {
            float v2 = cj[r];
            v2 += __shfl_xor(v2, 1);
            v2 += __shfl_xor(v2, 2);
            v2 += __shfl_xor(v2, 4);
            v2 += __shfl_xor(v2, 8);
            if (lr == 0) cpart[wg][wl * 16 + ls * 4 + r] = v2;
        }
        LGKM0(); SB();
        __builtin_amdgcn_s_barrier();   // cpart visible
        SB();
        if (tid < 64) {
            int j = t * 64 + tid;
            if (j < N_) cpout[j] = cpart[0][tid] + cpart[1][tid];
        }
        if (t < 9) {
            VMCNT(0); SB();
            __builtin_amdgcn_s_barrier();   // K(t+1) ready + cpart reads done
            SB();
        }
    }
}

// ---------------------------------------------------------------------------
// Top-k per batch: UCB scores (sum of 5 colsum partials, fixed order) +
// full bitonic sort (desc, ties -> lower index)
// ---------------------------------------------------------------------------
__global__ __launch_bounds__(512) void topk_kernel(const float* __restrict__ colsum_part,
                                                   const float* __restrict__ ucb_count,
                                                   const int* __restrict__ counter,
                                                   float* __restrict__ kept_out,
                                                   float* __restrict__ kvmask) {
    __shared__ float sv[1024];
    __shared__ int si[1024];
    int b = blockIdx.x, tid = threadIdx.x;
    float lc = logf((float)counter[0] + 1.0f);
    const size_t QSTRIDE = (size_t)(B_ * H_) * N_;
    for (int t = tid; t < 1024; t += 512) {
        if (t < N_ - 1) {
            int tok = t + 1;
            float accv = 0.f;
#pragma unroll
            for (int h = 0; h < H_; h++) {
                size_t base = (size_t)(b * H_ + h) * N_ + tok;
                float csv = 0.f;
#pragma unroll
                for (int qt = 0; qt < 5; qt++)
                    csv += colsum_part[qt * QSTRIDE + base];
                float patch = csv * (1.0f / (float)N_);
                float cnt = ucb_count[h * N_ + tok];
                float expl = sqrtf(lc / (cnt + 1e-6f));
                accv += patch + expl;
            }
            sv[t] = accv * (1.0f / (float)H_);
            si[t] = t;
        } else {
            sv[t] = -INFINITY;
            si[t] = 1 << 20;
        }
    }
    __syncthreads();
    for (int kk = 2; kk <= 1024; kk <<= 1) {
        for (int jj = kk >> 1; jj > 0; jj >>= 1) {
            for (int t = tid; t < 1024; t += 512) {
                int ixj = t ^ jj;
                if (ixj > t) {
                    float v1 = sv[t], v2 = sv[ixj];
                    int i1 = si[t], i2 = si[ixj];
                    bool before21 = (v2 > v1) || (v2 == v1 && i2 < i1);
                    bool dirDesc = ((t & kk) == 0);
                    if (before21 == dirDesc) {
                        sv[t] = v2; sv[ixj] = v1;
                        si[t] = i2; si[ixj] = i1;
                    }
                }
            }
            __syncthreads();
        }
    }
    for (int r = tid; r < KKEEP; r += 512) {
        int tok = si[r] + 1;
        kept_out[b * KKEEP + r] = (float)tok;
        kvmask[b * N_ + tok] = 1.0f;
    }
    if (tid == 0) kvmask[b * N_] = 1.0f;  // CLS always kept
}

// ---------------------------------------------------------------------------
// Pass CTX (+score_delta tail blocks): masked renormalized context -> bf16
// in TILED PRE-SWIZZLED layout.  Single-buffered K/V (4 blocks/CU).
// ---------------------------------------------------------------------------
__global__ __launch_bounds__(512) void attn_ctx_mfma(const ushort* __restrict__ qh,
                                                     const ushort* __restrict__ ql,
                                                     const ushort* __restrict__ kh,
                                                     const ushort* __restrict__ vtp,
                                                     const float* __restrict__ kvmask,
                                                     ushort* __restrict__ ctxb,
                                                     float* __restrict__ sd) {
    if (blockIdx.x >= 5 * B_ * H_) {
        int idx = (blockIdx.x - 5 * B_ * H_) * 512 + threadIdx.x;
        if (idx < H_ * N_) {
            int n = idx % N_;
            float d = 0.f;
            if (n != 0) {
#pragma unroll
                for (int b = 0; b < B_; b++) d += kvmask[b * N_ + n];
            }
            sd[idx] = d * (1.0f / (float)B_);
        }
        return;
    }
    __shared__ ushort Kh[4096], Vt[4096];
    __shared__ ushort Pl[2][4096];
    __shared__ float mkAll[640];
    float (*red)[64] = (float(*)[64])&Pl[0][0];
    float* inv = (float*)&Pl[1][0];
    const int bid = xcd_swz(blockIdx.x, 5 * B_ * H_);
    const int bh = bid / 5, q0 = (bid % 5) * 128;
    const int b = bh / H_, h = bh % H_;
    const int tid = threadIdx.x, lane = tid & 63, wv = tid >> 6;
    const int wg = wv >> 2, wl = wv & 3;
    const int lr = lane & 15, ls = lane >> 4;
    const size_t bho = (size_t)bh * PLROW;
    const ushort* qhp = qh + bho; const ushort* qlp = ql + bho;
    const ushort* khp = kh + bho;
    const ushort* vtb = vtp + (size_t)bh * 10 * 4096;
    ushort* PlS = &Pl[0][0];
    for (int i2 = tid; i2 < 640; i2 += 512)
        mkAll[i2] = (i2 < N_) ? kvmask[(size_t)b * N_ + i2] : 0.f;
    auto qrow = [&](int rr) { return (size_t)min(q0 + wv * 16 + rr * 8 + (lane >> 3), N_ - 1) * 64 + (lane & 7) * 8; };
    bf16x8_t fqh[4][2], fql[4][2];
    gload16(qhp + qrow(0), &PlS[wv * 1024]);
    gload16(qhp + qrow(1), &PlS[wv * 1024 + 512]);
    VMCNT(0); __syncthreads();
#pragma unroll
    for (int i = 0; i < 4; i++)
#pragma unroll
        for (int c = 0; c < 2; c++)
            fqh[i][c] = fragT(PlS, wg * 64 + i * 16 + lr, c, ls);
    __syncthreads();
    gload16(qlp + qrow(0), &PlS[wv * 1024]);
    gload16(qlp + qrow(1), &PlS[wv * 1024 + 512]);
    VMCNT(0); __syncthreads();
#pragma unroll
    for (int i = 0; i < 4; i++)
#pragma unroll
        for (int c = 0; c < 2; c++)
            fql[i][c] = fragT(PlS, wg * 64 + i * 16 + lr, c, ls);
    __syncthreads();
    auto krow = [&](int j0) { return (size_t)min(j0 + wv * 8 + (lane >> 3), N_ - 1) * 64 + (lane & 7) * 8; };
    auto stageKV = [&](int t) {
        gload16(khp + krow(t * 64), &Kh[wv * 512]);
        gload16(vtb + (size_t)t * 4096 + wv * 512 + lane * 8, &Vt[wv * 512]);
    };
    float mq[4];
#pragma unroll
    for (int i = 0; i < 4; i++) mq[i] = mkAll[q0 + wg * 64 + i * 16 + lr];
    stageKV(0);
    VMCNT(0);
    SB(); __builtin_amdgcn_s_barrier(); SB();
    f32x4_t acc[4] = {};
    float psums[4] = {0.f, 0.f, 0.f, 0.f};
#pragma unroll 1
    for (int t = 0; t < 10; ++t) {
        bf16x8_t fkh[2], fv[2];
#pragma unroll
        for (int c = 0; c < 2; c++) {
            fkh[c] = fragT(Kh, wl * 16 + lr, c, ls);
            fv[c]  = fragT(Vt, wl * 16 + lr, c, ls);
        }
        LGKM0(); SB();
        __builtin_amdgcn_s_barrier();       // all waves' K/V reads retired
        SB();
        if (t < 9) stageKV(t + 1);          // async overwrite, hidden
        int jloc = wl * 16 + ls * 4;
        float jmv[4], jbias[4];
#pragma unroll
        for (int r = 0; r < 4; r++) {
            int j = t * 64 + jloc + r;
            jmv[r] = mkAll[t * 64 + jloc + r];
            jbias[r] = (j < N_) ? 0.f : -16384.f;
        }
#pragma unroll
        for (int i = 0; i < 4; i++) {
            f32x4_t s = {0.f, 0.f, 0.f, 0.f};
            __builtin_amdgcn_s_setprio(1);
#pragma unroll
            for (int c = 0; c < 2; c++) {
                s = mfma_bf16(fkh[c], fqh[i][c], s);
                s = mfma_bf16(fkh[c], fql[i][c], s);
            }
            __builtin_amdgcn_s_setprio(0);
            bf16x4_t pb;
            float mqi = mq[i];
#pragma unroll
            for (int r = 0; r < 4; r++) {
                float p = __builtin_amdgcn_exp2f(s[r] + jbias[r]) * fmaxf(mqi, jmv[r]);
                psums[i] += p;
                pb[r] = (__bf16)p;
            }
            int row = i * 16 + lr;
            int slot = ((wl << 1) + (ls >> 1)) ^ (row & 7);
            *(u32x2_t*)&Pl[wg][(row << 6) + (slot << 3) + ((ls & 1) << 2)] =
                __builtin_bit_cast(u32x2_t, pb);
        }
        SB(); LGKM0(); SB();
        __builtin_amdgcn_s_barrier();       // P visible, vmcnt untouched
        SB();
        __builtin_amdgcn_s_setprio(1);
#pragma unroll
        for (int i = 0; i < 4; i++) {
            bf16x8_t fp0 = fragT(Pl[wg], i * 16 + lr, 0, ls);
            bf16x8_t fp1 = fragT(Pl[wg], i * 16 + lr, 1, ls);
            acc[i] = mfma_bf16(fv[0], fp0, acc[i]);
            acc[i] = mfma_bf16(fv[1], fp1, acc[i]);
        }
        __builtin_amdgcn_s_setprio(0);
        if (t < 9) {
            VMCNT(0); SB();
            __builtin_amdgcn_s_barrier();   // new K/V ready
            SB();
        }
    }
    __syncthreads();
#pragma unroll
    for (int i = 0; i < 4; i++) {
        float v2 = psums[i];
        v2 += __shfl_xor(v2, 16);
        v2 += __shfl_xor(v2, 32);
        if (ls == 0) red[wv][i * 16 + lr] = v2;
    }
    __syncthreads();
    if (tid < 128) {
        int grp = tid >> 6, qlc = tid & 63;
        float t2 = red[grp * 4 + 0][qlc] + red[grp * 4 + 1][qlc] +
                   red[grp * 4 + 2][qlc] + red[grp * 4 + 3][qlc];
        inv[tid] = 1.0f / (t2 + 1e-8f);
    }
    __syncthreads();
#pragma unroll
    for (int i = 0; i < 4; i++) {
        int qn = q0 + wg * 64 + i * 16 + lr;
        if (qn < N_) {
            float rn = inv[wg * 64 + i * 16 + lr];
            bf16x4_t ov;
            ov[0] = (__bf16)(acc[i][0] * rn);
            ov[1] = (__bf16)(acc[i][1] * rn);
            ov[2] = (__bf16)(acc[i][2] * rn);
            ov[3] = (__bf16)(acc[i][3] * rn);
            int m = b * N_ + qn;
            int col = h * D_ + wl * 16 + ls * 4;
            int mt = m >> 7, rowl = m & 127;
            int kt2 = col >> 5, c32 = col & 31;
            int phys = (c32 >> 3) ^ ((rowl >> 1) & 3);
            size_t off = ((size_t)(mt * NKT + kt2)) * 4096 + rowl * 32 + phys * 8 + (c32 & 7);
            *(u32x2_t*)&ctxb[off] = __builtin_bit_cast(u32x2_t, ov);
        }
    }
}

// ---------------------------------------------------------------------------
// MFMA GEMM 2 (plain bf16, tiled pre-swizzled A and B): counted-vmcnt pipeline
// out = context_bf16 @ Wproj^T + bproj
// ---------------------------------------------------------------------------
__global__ __launch_bounds__(256) void gemm_proj_mfma(const ushort* __restrict__ Apl,
                                                      const ushort* __restrict__ Bpl,
                                                      const float* __restrict__ bias,
                                                      float* __restrict__ out) {
    __shared__ ushort Ab[2][4096], Bb[2][4096];
    const int bid = xcd_swz(blockIdx.x, 6 * 73);
    const int bx = bid % 6, by = bid / 6;
    const int tid = threadIdx.x;
    const int lane = tid & 63, wave = tid >> 6;
    const int wr = wave >> 1, wc = wave & 1;
    const int lr = lane & 15, ls = lane >> 4;
    const int m0 = by * 128, n0 = bx * 128;
    const int o0 = wave * 1024, o1 = o0 + 512;
    const int la = lane * 8;
    const size_t abase = (size_t)by * NKT * 4096;
    const size_t bbase = (size_t)bx * NKT * 4096;
    f32x4_t acc[4][4] = {};

    auto stage = [&](int buf, int kt) {
        const size_t ta = abase + (size_t)kt * 4096;
        const size_t tb = bbase + (size_t)kt * 4096;
        gload16(Apl + ta + o0 + la, &Ab[buf][o0]);
        gload16(Apl + ta + o1 + la, &Ab[buf][o1]);
        gload16(Bpl + tb + o0 + la, &Bb[buf][o0]);
        gload16(Bpl + tb + o1 + la, &Bb[buf][o1]);
    };
    stage(0, 0);
#pragma unroll 1
    for (int kt = 0; kt < NKT; ++kt) {
        const int cur = kt & 1;
        if (kt + 1 < NKT) {
            stage(cur ^ 1, kt + 1);
            VMCNT(4);
        } else {
            VMCNT(0);
        }
        SB();
        __builtin_amdgcn_s_barrier();
        SB();
        bf16x8_t fa[4], fb[4];
#pragma unroll
        for (int i = 0; i < 4; i++) {
            int rowA = wr * 64 + i * 16 + lr;
            int pa = ls ^ ((rowA >> 1) & 3);
            fa[i] = __builtin_bit_cast(bf16x8_t, *(const u32x4_t*)&Ab[cur][rowA * 32 + pa * 8]);
            int rowB = wc * 64 + i * 16 + lr;
            int pb = ls ^ ((rowB >> 1) & 3);
            fb[i] = __builtin_bit_cast(bf16x8_t, *(const u32x4_t*)&Bb[cur][rowB * 32 + pb * 8]);
        }
#pragma unroll
        for (int i = 0; i < 4; i++)
#pragma unroll
            for (int j = 0; j < 4; j++)
                acc[i][j] = mfma_bf16(fa[i], fb[j], acc[i][j]);
        if (kt + 1 < NKT) {
            SB();
            __builtin_amdgcn_s_barrier();
        }
    }
#pragma unroll
    for (int j = 0; j < 4; j++) {
        int ng = n0 + wc * 64 + j * 16 + lr;
        float bb = bias[ng];
#pragma unroll
        for (int i = 0; i < 4; i++) {
            int mg0 = m0 + wr * 64 + i * 16 + ls * 4;
#pragma unroll
            for (int r = 0; r < 4; r++) {
                int m = mg0 + r;
                if (m < M_TOT) out[(size_t)m * C_ + ng] = acc[i][j][r] + bb;
            }
        }
    }
}

// ---------------------------------------------------------------------------
extern "C" void kernel_launch(void* const* d_in, const int* in_sizes, int n_in,
                              void* d_out, int out_size, void* d_ws, size_t ws_size,
                              hipStream_t stream) {
    const float* x     = (const float*)d_in[0];
    const float* ucb   = (const float*)d_in[1];
    const float* Wqkv  = (const float*)d_in[2];
    const float* Wproj = (const float*)d_in[3];
    const float* bproj = (const float*)d_in[4];
    const int*   counter = (const int*)d_in[5];

    const size_t BHN  = (size_t)B_ * H_ * N_;       // 110,784
    const size_t XPL  = (size_t)(73 * 128) * C_;    // 7,176,192
    const size_t WPL  = (size_t)3 * C_ * C_;        // 1,769,472
    const size_t WPJ  = (size_t)C_ * C_;            // 589,824 (= 144 tiles)
    const size_t PLN  = (size_t)192 * PLROW;        // 7,090,176 ushorts per plane
    const size_t VTSZ = (size_t)192 * 10 * 4096;    // 7,864,320 ushorts

    ushort* qhp  = (ushort*)d_ws;
    ushort* qlp  = qhp + PLN;
    ushort* khp  = qlp + PLN;
    ushort* klp  = khp + PLN;
    ushort* vtp  = klp + PLN;
    ushort* XplH = vtp + VTSZ;
    ushort* XplL = XplH + XPL;
    ushort* ctxb = XplH;                 // alias: X planes dead after gemm_qkv
    ushort* WplH = XplL + XPL;
    ushort* WplL = WplH + WPL;
    ushort* Wpjb = WplL + WPL;
    float*  colsum_part = (float*)(Wpjb + WPJ);      // 5 * BHN floats
    float*  kvmask = colsum_part + 5 * BHN;
    size_t need = ((char*)(kvmask + (size_t)B_ * N_)) - (char*)d_ws;
    if (ws_size < need) {
        fprintf(stderr, "kernel_launch: ws too small, need %zu have %zu\n",
                need, ws_size);
        return;
    }

    float* out  = (float*)d_out;
    float* sd   = out + (size_t)B_ * N_ * C_;
    float* kept = sd + (size_t)H_ * N_;

    pack_all_kernel<<<NXP + NWP + NPJ + NZ, 256, 0, stream>>>(
        x, Wqkv, Wproj, XplH, XplL, WplH, WplL, Wpjb, kvmask);

    gemm_qkv_mfma<<<18 * 73, 256, 0, stream>>>(XplH, XplL, WplH, WplL,
                                               qhp, qlp, khp, klp, vtp);
    attn_rc_mfma<<<5 * B_ * H_, 512, 0, stream>>>(qhp, qlp, khp, klp, colsum_part);
    topk_kernel<<<B_, 512, 0, stream>>>(colsum_part, ucb, counter, kept, kvmask);
    attn_ctx_mfma<<<5 * B_ * H_ + 14, 512, 0, stream>>>(qhp, qlp, khp, vtp,
                                                        kvmask, ctxb, sd);
    gemm_proj_mfma<<<6 * 73, 256, 0, stream>>>(ctxb, Wpjb, bproj, out);
}

// Round 21
// 270.955 us; speedup vs baseline: 1.0245x; 1.0245x over previous
//
#include <hip/hip_runtime.h>
#include <cstdio>
#include <cstdint>

// Problem constants
#define B_    16
#define N_    577
#define C_    768
#define H_    12
#define D_    64
#define KKEEP 288            // max(1, int(576*0.5))
#define SCALE 0.125f         // 64^-0.5 (exact power of 2)
#define LOG2E 1.4426950408889634f
#define M_TOT (B_ * N_)      // 9232
#define NKT   24             // K tiles (768/32)
#define PLROW ((size_t)N_ * 64)       // q/k plane bh stride (ushorts)

typedef __bf16 bf16x8_t __attribute__((ext_vector_type(8)));
typedef __bf16 bf16x4_t __attribute__((ext_vector_type(4)));
typedef float  f32x4_t  __attribute__((ext_vector_type(4)));
typedef unsigned int u32x4_t __attribute__((ext_vector_type(4)));
typedef unsigned int u32x2_t __attribute__((ext_vector_type(2)));

__device__ __forceinline__ f32x4_t mfma_bf16(bf16x8_t a, bf16x8_t b, f32x4_t c) {
    return __builtin_amdgcn_mfma_f32_16x16x32_bf16(a, b, c, 0, 0, 0);
}

// async global->LDS, 16B per lane (lds dest = wave-uniform base + lane*16)
__device__ __forceinline__ void gload16(const ushort* g, ushort* l) {
    __builtin_amdgcn_global_load_lds(
        (const __attribute__((address_space(1))) void*)g,
        (__attribute__((address_space(3))) void*)l, 16, 0, 0);
}
#define VMCNT(n) asm volatile("s_waitcnt vmcnt(" #n ")" ::: "memory")
#define LGKM0()  asm volatile("s_waitcnt lgkmcnt(0)" ::: "memory")
#define SB() __builtin_amdgcn_sched_barrier(0)

// bijective XCD-aware block remap (m204)
__device__ __forceinline__ int xcd_swz(int bid, int nwg) {
    int q = nwg >> 3, r = nwg & 7;
    int xcd = bid & 7, off = bid >> 3;
    int base = (xcd < r) ? xcd * (q + 1) : r * (q + 1) + (xcd - r) * q;
    return base + off;
}

// RTZ split of f32 into two bf16 bit patterns (x ~= hi + lo, err ~2^-16 |x|)
__device__ __forceinline__ void splitf(float x, unsigned int &hi, unsigned int &lo) {
    unsigned int u = __float_as_uint(x);
    hi = u >> 16;
    float r = x - __uint_as_float(u & 0xffff0000u);
    lo = __float_as_uint(r) >> 16;
}
__device__ __forceinline__ unsigned int bf16rne(float x) {
    unsigned int u = __float_as_uint(x);
    return (u + 0x7fffu + ((u >> 16) & 1u)) >> 16;
}

// ---------------------------------------------------------------------------
// Pack one 128x32 tile of f32 [nrows x 768] into split hi/lo bf16 planes,
// pre-swizzled to the fragT layout.
// ---------------------------------------------------------------------------
__device__ __forceinline__ void pack_tile(const float* __restrict__ src,
                                          ushort* __restrict__ dH,
                                          ushort* __restrict__ dL,
                                          int nrows, int tile) {
    int kt = tile % NKT, mt = tile / NKT;
    int w = threadIdx.x;
    int row = w >> 1, h = w & 1;
    int m = mt * 128 + row;
    int sw = (row >> 1) & 3;
    float f[16];
    if (m < nrows) {
        const float* s = src + (size_t)m * C_ + kt * 32;
        int sa = (2 * h) ^ sw, sb = (2 * h + 1) ^ sw;
        *(float4*)&f[0]  = *(const float4*)(s + sa * 8);
        *(float4*)&f[4]  = *(const float4*)(s + sa * 8 + 4);
        *(float4*)&f[8]  = *(const float4*)(s + sb * 8);
        *(float4*)&f[12] = *(const float4*)(s + sb * 8 + 4);
    } else {
#pragma unroll
        for (int i = 0; i < 16; i++) f[i] = 0.f;
    }
    unsigned hi[16], lo[16];
#pragma unroll
    for (int i = 0; i < 16; i++) splitf(f[i], hi[i], lo[i]);
    u32x4_t h0 = {hi[0] | (hi[1] << 16), hi[2] | (hi[3] << 16),
                  hi[4] | (hi[5] << 16), hi[6] | (hi[7] << 16)};
    u32x4_t h1 = {hi[8] | (hi[9] << 16), hi[10] | (hi[11] << 16),
                  hi[12] | (hi[13] << 16), hi[14] | (hi[15] << 16)};
    u32x4_t l0 = {lo[0] | (lo[1] << 16), lo[2] | (lo[3] << 16),
                  lo[4] | (lo[5] << 16), lo[6] | (lo[7] << 16)};
    u32x4_t l1 = {lo[8] | (lo[9] << 16), lo[10] | (lo[11] << 16),
                  lo[12] | (lo[13] << 16), lo[14] | (lo[15] << 16)};
    size_t dbase = (size_t)tile * 4096 + row * 32;
    *(u32x4_t*)&dH[dbase + (2 * h) * 8]     = h0;
    *(u32x4_t*)&dH[dbase + (2 * h + 1) * 8] = h1;
    *(u32x4_t*)&dL[dbase + (2 * h) * 8]     = l0;
    *(u32x4_t*)&dL[dbase + (2 * h + 1) * 8] = l1;
}

// Pack one 128x32 tile, single bf16 plane (RNE), pre-swizzled.
__device__ __forceinline__ void pack_tile_rne(const float* __restrict__ src,
                                              ushort* __restrict__ dst,
                                              int nrows, int tile) {
    int kt = tile % NKT, mt = tile / NKT;
    int w = threadIdx.x;
    int row = w >> 1, h = w & 1;
    int m = mt * 128 + row;
    int sw = (row >> 1) & 3;
    float f[16];
    if (m < nrows) {
        const float* s = src + (size_t)m * C_ + kt * 32;
        int sa = (2 * h) ^ sw, sb = (2 * h + 1) ^ sw;
        *(float4*)&f[0]  = *(const float4*)(s + sa * 8);
        *(float4*)&f[4]  = *(const float4*)(s + sa * 8 + 4);
        *(float4*)&f[8]  = *(const float4*)(s + sb * 8);
        *(float4*)&f[12] = *(const float4*)(s + sb * 8 + 4);
    } else {
#pragma unroll
        for (int i = 0; i < 16; i++) f[i] = 0.f;
    }
    unsigned hi[16];
#pragma unroll
    for (int i = 0; i < 16; i++) hi[i] = bf16rne(f[i]);
    u32x4_t h0 = {hi[0] | (hi[1] << 16), hi[2] | (hi[3] << 16),
                  hi[4] | (hi[5] << 16), hi[6] | (hi[7] << 16)};
    u32x4_t h1 = {hi[8] | (hi[9] << 16), hi[10] | (hi[11] << 16),
                  hi[12] | (hi[13] << 16), hi[14] | (hi[15] << 16)};
    size_t dbase = (size_t)tile * 4096 + row * 32;
    *(u32x4_t*)&dst[dbase + (2 * h) * 8]     = h0;
    *(u32x4_t*)&dst[dbase + (2 * h + 1) * 8] = h1;
}

#define NXP 1752              // 73*24 X tiles
#define NWP 432               // 18*24 W tiles
#define NPJ 144               // 6*24 Wproj tiles
#define NZ  37                // ceil(9232/256)

// ---------------------------------------------------------------------------
// Merged prepass: X pack | Wqkv pack | Wproj tiled RNE | kvmask zero
// ---------------------------------------------------------------------------
__global__ __launch_bounds__(256) void pack_all_kernel(const float* __restrict__ x,
                                                       const float* __restrict__ Wqkv,
                                                       const float* __restrict__ Wproj,
                                                       ushort* __restrict__ XplH,
                                                       ushort* __restrict__ XplL,
                                                       ushort* __restrict__ WplH,
                                                       ushort* __restrict__ WplL,
                                                       ushort* __restrict__ Wpjb,
                                                       float* __restrict__ kvmask) {
    int bid = blockIdx.x;
    if (bid < NXP) {
        pack_tile(x, XplH, XplL, M_TOT, bid);
    } else if (bid < NXP + NWP) {
        pack_tile(Wqkv, WplH, WplL, 3 * C_, bid - NXP);
    } else if (bid < NXP + NWP + NPJ) {
        pack_tile_rne(Wproj, Wpjb, C_, bid - NXP - NWP);
    } else {
        int i = (bid - NXP - NWP - NPJ) * 256 + threadIdx.x;
        if (i < B_ * N_) kvmask[i] = 0.f;
    }
}

// ===========================================================================
// 64x64 bf16 LDS tiles: 64 ushort/row, 8 slots of 8; phys slot = logical^(row&7)
// ===========================================================================
__device__ __forceinline__ bf16x8_t fragT(const ushort* H, int row, int c, int ls) {
    int phys = ((c << 2) + ls) ^ (row & 7);
    return __builtin_bit_cast(bf16x8_t, *(const u32x4_t*)&H[(row << 6) + (phys << 3)]);
}

// ---------------------------------------------------------------------------
// Merged MFMA GEMM 1: qkv = x @ Wqkv^T, 18x73 tile grid.
// A planes double-buffered (counted), B planes single-buffered (issue-early)
// -> 48KB LDS -> 3 blocks/CU.
// n-tile < 12: q/k columns (3-term split) -> qh/ql/kh/kl planes (q pre-scaled)
// n-tile >= 12: v columns (2-term) -> vt tiled-swizzled [bh][10][4096]
// ---------------------------------------------------------------------------
__global__ __launch_bounds__(256) void gemm_qkv_mfma(const ushort* __restrict__ XplH,
                                                     const ushort* __restrict__ XplL,
                                                     const ushort* __restrict__ WplH,
                                                     const ushort* __restrict__ WplL,
                                                     ushort* __restrict__ qhp,
                                                     ushort* __restrict__ qlp,
                                                     ushort* __restrict__ khp,
                                                     ushort* __restrict__ klp,
                                                     ushort* __restrict__ vtp) {
    __shared__ ushort SMEM[24576];     // 48KB
    ushort* Ah = SMEM;                 // [2][4096]
    ushort* Al = SMEM + 8192;          // [2][4096]
    ushort* Bh = SMEM + 16384;         // [4096] single
    ushort* Bl = SMEM + 20480;         // [4096] single
    const int bid = xcd_swz(blockIdx.x, 18 * 73);
    const int bx = bid % 18, by = bid / 18;
    const int tid = threadIdx.x;
    const int lane = tid & 63, wave = tid >> 6;
    const int wr = wave >> 1, wc = wave & 1;
    const int lr = lane & 15, ls = lane >> 4;
    const int m0 = by * 128;
    const int o0 = wave * 1024, o1 = o0 + 512;
    const int la = lane * 8;
    const size_t abase = (size_t)by * NKT * 4096;
    const size_t bbase = (size_t)bx * NKT * 4096;
    f32x4_t acc[4][4] = {};

    if (bx < 12) {
        // ---------------- q/k path: 3-term split ----------------
        auto stageA = [&](int buf, int kt) {
            const size_t ta = abase + (size_t)kt * 4096;
            gload16(XplH + ta + o0 + la, &Ah[buf * 4096 + o0]);
            gload16(XplH + ta + o1 + la, &Ah[buf * 4096 + o1]);
            gload16(XplL + ta + o0 + la, &Al[buf * 4096 + o0]);
            gload16(XplL + ta + o1 + la, &Al[buf * 4096 + o1]);
        };
        auto stageB = [&](int kt) {
            const size_t tb = bbase + (size_t)kt * 4096;
            gload16(WplH + tb + o0 + la, &Bh[o0]);
            gload16(WplH + tb + o1 + la, &Bh[o1]);
            gload16(WplL + tb + o0 + la, &Bl[o0]);
            gload16(WplL + tb + o1 + la, &Bl[o1]);
        };
        stageA(0, 0);
        stageB(0);
        VMCNT(0);
        SB(); __builtin_amdgcn_s_barrier(); SB();
#pragma unroll 1
        for (int kt = 0; kt < NKT; ++kt) {
            const int cur = kt & 1;
            if (kt + 1 < NKT) stageA(cur ^ 1, kt + 1);   // other buf, safe now
            bf16x8_t fah[4], fal[4], fbh[4], fbl[4];
#pragma unroll
            for (int i = 0; i < 4; i++) {
                int rowA = wr * 64 + i * 16 + lr;
                int pa = ls ^ ((rowA >> 1) & 3);
                fah[i] = __builtin_bit_cast(bf16x8_t, *(const u32x4_t*)&Ah[cur * 4096 + rowA * 32 + pa * 8]);
                fal[i] = __builtin_bit_cast(bf16x8_t, *(const u32x4_t*)&Al[cur * 4096 + rowA * 32 + pa * 8]);
                int rowB = wc * 64 + i * 16 + lr;
                int pb = ls ^ ((rowB >> 1) & 3);
                fbh[i] = __builtin_bit_cast(bf16x8_t, *(const u32x4_t*)&Bh[rowB * 32 + pb * 8]);
                fbl[i] = __builtin_bit_cast(bf16x8_t, *(const u32x4_t*)&Bl[rowB * 32 + pb * 8]);
            }
            LGKM0(); SB();
            __builtin_amdgcn_s_barrier();   // B frag reads retired block-wide
            SB();
            if (kt + 1 < NKT) stageB(kt + 1);  // overwrite single B buf (async)
            __builtin_amdgcn_s_setprio(1);
#pragma unroll
            for (int i = 0; i < 4; i++)
#pragma unroll
                for (int j = 0; j < 4; j++) {
                    acc[i][j] = mfma_bf16(fah[i], fbh[j], acc[i][j]);
                    acc[i][j] = mfma_bf16(fah[i], fbl[j], acc[i][j]);
                    acc[i][j] = mfma_bf16(fal[i], fbh[j], acc[i][j]);
                }
            __builtin_amdgcn_s_setprio(0);
            if (kt + 1 < NKT) {
                VMCNT(0); SB();
                __builtin_amdgcn_s_barrier();   // A(t+1), B(t+1) ready
                SB();
            }
        }
        // coalesced epilogue: two half-tile u32 bounce rounds (32KB each)
        const int n0 = bx * 128;
        const int s = n0 / C_;
        __syncthreads();
        unsigned* T = (unsigned*)SMEM;   // 64 x 128 u32 = 32KB
        const float sc = (s == 0) ? SCALE * LOG2E : 1.0f;
        ushort* dh = (s == 1) ? khp : qhp;
        ushort* dl = (s == 1) ? klp : qlp;
        const int hh0 = (n0 % C_) / D_;
#pragma unroll 1
        for (int round = 0; round < 2; ++round) {
            if (wr == round) {
#pragma unroll
                for (int j = 0; j < 4; j++) {
                    int nl = wc * 64 + j * 16 + lr;
#pragma unroll
                    for (int i = 0; i < 4; i++) {
#pragma unroll
                        for (int r = 0; r < 4; r++) {
                            int ml = wr * 64 + i * 16 + ls * 4 + r;   // full row id
                            unsigned hi, lo;
                            splitf(acc[i][j][r] * sc, hi, lo);
                            int idx = (ml & 63) * 128 +
                                      ((((nl >> 3) ^ ((ml >> 2) & 7)) << 3) | (nl & 7));
                            T[idx] = hi | (lo << 16);
                        }
                    }
                }
            }
            __syncthreads();
#pragma unroll
            for (int it = 0; it < 4; ++it) {
                int g = it * 256 + tid;          // 1024 slots = 64 rows x 16
                int sl = g & 7;
                int m_local64 = (g >> 3) & 63;
                int hh_half = g >> 9;            // 0 or 1
                int m_local = round * 64 + m_local64;
                int m = m0 + m_local;
                if (m < M_TOT) {
                    int b = m / N_, n = m % N_;
                    int dg = sl ^ (n & 7);
                    int grp = (hh_half * 8 + dg) ^ ((m_local >> 2) & 7);
                    const unsigned* src = &T[m_local64 * 128 + grp * 8];
                    u32x4_t a = *(const u32x4_t*)src;
                    u32x4_t bvv = *(const u32x4_t*)(src + 4);
                    u32x4_t hiv = {(a[0] & 0xffffu) | (a[1] << 16),
                                   (a[2] & 0xffffu) | (a[3] << 16),
                                   (bvv[0] & 0xffffu) | (bvv[1] << 16),
                                   (bvv[2] & 0xffffu) | (bvv[3] << 16)};
                    u32x4_t lov = {(a[0] >> 16) | (a[1] & 0xffff0000u),
                                   (a[2] >> 16) | (a[3] & 0xffff0000u),
                                   (bvv[0] >> 16) | (bvv[1] & 0xffff0000u),
                                   (bvv[2] >> 16) | (bvv[3] & 0xffff0000u)};
                    size_t off = (size_t)(b * H_ + hh0 + hh_half) * PLROW + (size_t)n * 64 + sl * 8;
                    *(u32x4_t*)&dh[off] = hiv;
                    *(u32x4_t*)&dl[off] = lov;
                }
            }
            if (round == 0) __syncthreads();
        }
    } else {
        // ---------------- v path: 2-term split ----------------
        auto stageA = [&](int buf, int kt) {
            const size_t ta = abase + (size_t)kt * 4096;
            gload16(XplH + ta + o0 + la, &Ah[buf * 4096 + o0]);
            gload16(XplH + ta + o1 + la, &Ah[buf * 4096 + o1]);
            gload16(XplL + ta + o0 + la, &Al[buf * 4096 + o0]);
            gload16(XplL + ta + o1 + la, &Al[buf * 4096 + o1]);
        };
        auto stageB = [&](int kt) {
            const size_t tb = bbase + (size_t)kt * 4096;
            gload16(WplH + tb + o0 + la, &Bh[o0]);
            gload16(WplH + tb + o1 + la, &Bh[o1]);
        };
        stageA(0, 0);
        stageB(0);
        VMCNT(0);
        SB(); __builtin_amdgcn_s_barrier(); SB();
#pragma unroll 1
        for (int kt = 0; kt < NKT; ++kt) {
            const int cur = kt & 1;
            if (kt + 1 < NKT) stageA(cur ^ 1, kt + 1);
            bf16x8_t fah[4], fal[4], fbh[4];
#pragma unroll
            for (int i = 0; i < 4; i++) {
                int rowA = wr * 64 + i * 16 + lr;
                int pa = ls ^ ((rowA >> 1) & 3);
                fah[i] = __builtin_bit_cast(bf16x8_t, *(const u32x4_t*)&Ah[cur * 4096 + rowA * 32 + pa * 8]);
                fal[i] = __builtin_bit_cast(bf16x8_t, *(const u32x4_t*)&Al[cur * 4096 + rowA * 32 + pa * 8]);
                int rowB = wc * 64 + i * 16 + lr;
                int pb = ls ^ ((rowB >> 1) & 3);
                fbh[i] = __builtin_bit_cast(bf16x8_t, *(const u32x4_t*)&Bh[rowB * 32 + pb * 8]);
            }
            LGKM0(); SB();
            __builtin_amdgcn_s_barrier();
            SB();
            if (kt + 1 < NKT) stageB(kt + 1);
            __builtin_amdgcn_s_setprio(1);
#pragma unroll
            for (int i = 0; i < 4; i++)
#pragma unroll
                for (int j = 0; j < 4; j++) {
                    acc[i][j] = mfma_bf16(fah[i], fbh[j], acc[i][j]);
                    acc[i][j] = mfma_bf16(fal[i], fbh[j], acc[i][j]);
                }
            __builtin_amdgcn_s_setprio(0);
            if (kt + 1 < NKT) {
                VMCNT(0); SB();
                __builtin_amdgcn_s_barrier();
                SB();
            }
        }
        const int n0v = (bx - 12) * 128;
#pragma unroll
        for (int j = 0; j < 4; j++) {
            int ng = n0v + wc * 64 + j * 16 + lr;
            int hh = ng / D_;
            int d = ng % D_;
#pragma unroll
            for (int i = 0; i < 4; i++) {
                int mg0 = m0 + wr * 64 + i * 16 + ls * 4;
#pragma unroll
                for (int r = 0; r < 4; r++) {
                    int m = mg0 + r;
                    if (m < M_TOT) {
                        int b = m / N_, n = m % N_;
                        int jt = n >> 6, jl = n & 63;
                        size_t off = ((size_t)(b * H_ + hh) * 10 + jt) * 4096 +
                                     (size_t)d * 64 + (((jl >> 3) ^ (d & 7)) << 3) + (jl & 7);
                        vtp[off] = __builtin_bit_cast(unsigned short, (__bf16)acc[i][j][r]);
                    }
                }
            }
        }
    }
}

// ---------------------------------------------------------------------------
// Pass R: w[bh][q] = 1 / sum_j exp2(s)  — 128-q tile, single-buffered K,
// issue-early staging (loads hidden under MFMA+exp).
// ---------------------------------------------------------------------------
__global__ __launch_bounds__(512) void attn_rowsum_mfma(const ushort* __restrict__ qh,
                                                        const ushort* __restrict__ ql,
                                                        const ushort* __restrict__ kh,
                                                        const ushort* __restrict__ kl,
                                                        float* __restrict__ w) {
    __shared__ ushort Qh[8192], Ql[8192];
    __shared__ ushort Kh[4096], Kl[4096];
    __shared__ float red[8][64];
    const int bid = xcd_swz(blockIdx.x, 5 * B_ * H_);
    const int bh = bid / 5, q0 = (bid % 5) * 128;
    const int tid = threadIdx.x, lane = tid & 63, wv = tid >> 6;
    const int wg = wv >> 2, wl = wv & 3;
    const int lr = lane & 15, ls = lane >> 4;
    const size_t bho = (size_t)bh * PLROW;
    const ushort* qhp = qh + bho; const ushort* qlp = ql + bho;
    const ushort* khp = kh + bho; const ushort* klp = kl + bho;
    auto qrow = [&](int rr) { return (size_t)min(q0 + wv * 16 + rr * 8 + (lane >> 3), N_ - 1) * 64 + (lane & 7) * 8; };
    gload16(qhp + qrow(0), &Qh[wv * 1024]);
    gload16(qhp + qrow(1), &Qh[wv * 1024 + 512]);
    gload16(qlp + qrow(0), &Ql[wv * 1024]);
    gload16(qlp + qrow(1), &Ql[wv * 1024 + 512]);
    auto krow = [&](int j0) { return (size_t)min(j0 + wv * 8 + (lane >> 3), N_ - 1) * 64 + (lane & 7) * 8; };
    auto stageK = [&](int j0) {
        gload16(khp + krow(j0), &Kh[wv * 512]);
        gload16(klp + krow(j0), &Kl[wv * 512]);
    };
    stageK(0);
    VMCNT(0);
    __syncthreads();
    bf16x8_t fqh[4][2], fql[4][2];
#pragma unroll
    for (int i = 0; i < 4; i++)
#pragma unroll
        for (int c = 0; c < 2; c++) {
            fqh[i][c] = fragT(Qh, wg * 64 + i * 16 + lr, c, ls);
            fql[i][c] = fragT(Ql, wg * 64 + i * 16 + lr, c, ls);
        }
    float rs[4] = {0.f, 0.f, 0.f, 0.f};
#pragma unroll 1
    for (int t = 0; t < 10; ++t) {
        bf16x8_t fkh[2], fkl[2];
#pragma unroll
        for (int c = 0; c < 2; c++) {
            fkh[c] = fragT(Kh, wl * 16 + lr, c, ls);
            fkl[c] = fragT(Kl, wl * 16 + lr, c, ls);
        }
        LGKM0(); SB();
        __builtin_amdgcn_s_barrier();   // all waves' K frag reads retired
        SB();
        if (t < 9) stageK((t + 1) * 64);  // async overwrite, hidden under MFMA
        int jbase = t * 64 + wl * 16 + ls * 4;
#pragma unroll
        for (int i = 0; i < 4; i++) {
            f32x4_t s = {0.f, 0.f, 0.f, 0.f};
            __builtin_amdgcn_s_setprio(1);
#pragma unroll
            for (int c = 0; c < 2; c++) {
                s = mfma_bf16(fkh[c], fqh[i][c], s);
                s = mfma_bf16(fkh[c], fql[i][c], s);
                s = mfma_bf16(fkl[c], fqh[i][c], s);
            }
            __builtin_amdgcn_s_setprio(0);
#pragma unroll
            for (int r = 0; r < 4; r++)
                rs[i] += (jbase + r < N_) ? __builtin_amdgcn_exp2f(s[r]) : 0.f;
        }
        if (t < 9) {
            VMCNT(0); SB();
            __builtin_amdgcn_s_barrier();   // new K visible
            SB();
        }
    }
#pragma unroll
    for (int i = 0; i < 4; i++) {
        float v2 = rs[i];
        v2 += __shfl_xor(v2, 16);
        v2 += __shfl_xor(v2, 32);
        if (ls == 0) red[wv][i * 16 + lr] = v2;
    }
    __syncthreads();
    if (tid < 128) {
        int grp = tid >> 6, qlc = tid & 63;
        float s = red[grp * 4 + 0][qlc] + red[grp * 4 + 1][qlc] +
                  red[grp * 4 + 2][qlc] + red[grp * 4 + 3][qlc];
        int qn = q0 + tid;
        if (qn < N_) w[(size_t)bh * N_ + qn] = 1.0f / s;
    }
}

// ---------------------------------------------------------------------------
// Pass CS: colsum[bh][j] = sum_q exp2(s)*w[q] — 128-j tile, single-buffered Q,
// issue-early staging.
// ---------------------------------------------------------------------------
__global__ __launch_bounds__(512) void attn_colsum_mfma(const ushort* __restrict__ qh,
                                                        const ushort* __restrict__ ql,
                                                        const ushort* __restrict__ kh,
                                                        const ushort* __restrict__ kl,
                                                        const float* __restrict__ w,
                                                        float* __restrict__ colsum) {
    __shared__ ushort KhS[8192], KlS[8192];
    __shared__ ushort Qh[4096], Ql[4096];
    __shared__ float wsAll[640];
    __shared__ float red[8][64];
    const int bid = xcd_swz(blockIdx.x, 5 * B_ * H_);
    const int bh = bid / 5, j0 = (bid % 5) * 128;
    const int tid = threadIdx.x, lane = tid & 63, wv = tid >> 6;
    const int wg = wv >> 2, wl = wv & 3;
    const int lr = lane & 15, ls = lane >> 4;
    const size_t bho = (size_t)bh * PLROW;
    const ushort* qhp = qh + bho; const ushort* qlp = ql + bho;
    const ushort* khp = kh + bho; const ushort* klp = kl + bho;
    auto krow = [&](int rr) { return (size_t)min(j0 + wv * 16 + rr * 8 + (lane >> 3), N_ - 1) * 64 + (lane & 7) * 8; };
    gload16(khp + krow(0), &KhS[wv * 1024]);
    gload16(khp + krow(1), &KhS[wv * 1024 + 512]);
    gload16(klp + krow(0), &KlS[wv * 1024]);
    gload16(klp + krow(1), &KlS[wv * 1024 + 512]);
    auto qrow2 = [&](int qt) { return (size_t)min(qt + wv * 8 + (lane >> 3), N_ - 1) * 64 + (lane & 7) * 8; };
    auto stageQ = [&](int qt) {
        gload16(qhp + qrow2(qt), &Qh[wv * 512]);
        gload16(qlp + qrow2(qt), &Ql[wv * 512]);
    };
    stageQ(0);
    for (int i2 = tid; i2 < 640; i2 += 512)
        wsAll[i2] = (i2 < N_) ? w[(size_t)bh * N_ + i2] : 0.f;
    VMCNT(0);
    __syncthreads();
    bf16x8_t fkh[4][2], fkl[4][2];
#pragma unroll
    for (int i = 0; i < 4; i++)
#pragma unroll
        for (int c = 0; c < 2; c++) {
            fkh[i][c] = fragT(KhS, wg * 64 + i * 16 + lr, c, ls);
            fkl[i][c] = fragT(KlS, wg * 64 + i * 16 + lr, c, ls);
        }
    float cs[4] = {0.f, 0.f, 0.f, 0.f};
#pragma unroll 1
    for (int t = 0; t < 10; ++t) {
        bf16x8_t fqh[2], fql[2];
#pragma unroll
        for (int c = 0; c < 2; c++) {
            fqh[c] = fragT(Qh, wl * 16 + lr, c, ls);
            fql[c] = fragT(Ql, wl * 16 + lr, c, ls);
        }
        float wq[4];
#pragma unroll
        for (int r = 0; r < 4; r++) wq[r] = wsAll[t * 64 + wl * 16 + ls * 4 + r];
        LGKM0(); SB();
        __builtin_amdgcn_s_barrier();
        SB();
        if (t < 9) stageQ((t + 1) * 64);
#pragma unroll
        for (int i = 0; i < 4; i++) {
            f32x4_t s = {0.f, 0.f, 0.f, 0.f};
            __builtin_amdgcn_s_setprio(1);
#pragma unroll
            for (int c = 0; c < 2; c++) {
                s = mfma_bf16(fqh[c], fkh[i][c], s);
                s = mfma_bf16(fql[c], fkh[i][c], s);
                s = mfma_bf16(fqh[c], fkl[i][c], s);
            }
            __builtin_amdgcn_s_setprio(0);
#pragma unroll
            for (int r = 0; r < 4; r++) cs[i] += __builtin_amdgcn_exp2f(s[r]) * wq[r];
        }
        if (t < 9) {
            VMCNT(0); SB();
            __builtin_amdgcn_s_barrier();
            SB();
        }
    }
#pragma unroll
    for (int i = 0; i < 4; i++) {
        float v2 = cs[i];
        v2 += __shfl_xor(v2, 16);
        v2 += __shfl_xor(v2, 32);
        if (ls == 0) red[wv][i * 16 + lr] = v2;
    }
    __syncthreads();
    if (tid < 128) {
        int grp = tid >> 6, jlc = tid & 63;
        float t2 = red[grp * 4 + 0][jlc] + red[grp * 4 + 1][jlc] +
                   red[grp * 4 + 2][jlc] + red[grp * 4 + 3][jlc];
        int jn = j0 + tid;
        if (jn < N_) colsum[(size_t)bh * N_ + jn] = t2;
    }
}

// ---------------------------------------------------------------------------
// Top-k per batch: UCB scores + full bitonic sort (desc, ties -> lower index)
// ---------------------------------------------------------------------------
__global__ __launch_bounds__(512) void topk_kernel(const float* __restrict__ colsum,
                                                   const float* __restrict__ ucb_count,
                                                   const int* __restrict__ counter,
                                                   float* __restrict__ kept_out,
                                                   float* __restrict__ kvmask) {
    __shared__ float sv[1024];
    __shared__ int si[1024];
    int b = blockIdx.x, tid = threadIdx.x;
    float lc = logf((float)counter[0] + 1.0f);
    for (int t = tid; t < 1024; t += 512) {
        if (t < N_ - 1) {
            int tok = t + 1;
            float accv = 0.f;
#pragma unroll
            for (int h = 0; h < H_; h++) {
                float csv = colsum[(size_t)(b * H_ + h) * N_ + tok];
                float patch = csv * (1.0f / (float)N_);
                float cnt = ucb_count[h * N_ + tok];
                float expl = sqrtf(lc / (cnt + 1e-6f));
                accv += patch + expl;
            }
            sv[t] = accv * (1.0f / (float)H_);
            si[t] = t;
        } else {
            sv[t] = -INFINITY;
            si[t] = 1 << 20;
        }
    }
    __syncthreads();
    for (int kk = 2; kk <= 1024; kk <<= 1) {
        for (int jj = kk >> 1; jj > 0; jj >>= 1) {
            for (int t = tid; t < 1024; t += 512) {
                int ixj = t ^ jj;
                if (ixj > t) {
                    float v1 = sv[t], v2 = sv[ixj];
                    int i1 = si[t], i2 = si[ixj];
                    bool before21 = (v2 > v1) || (v2 == v1 && i2 < i1);
                    bool dirDesc = ((t & kk) == 0);
                    if (before21 == dirDesc) {
                        sv[t] = v2; sv[ixj] = v1;
                        si[t] = i2; si[ixj] = i1;
                    }
                }
            }
            __syncthreads();
        }
    }
    for (int r = tid; r < KKEEP; r += 512) {
        int tok = si[r] + 1;
        kept_out[b * KKEEP + r] = (float)tok;
        kvmask[b * N_ + tok] = 1.0f;
    }
    if (tid == 0) kvmask[b * N_] = 1.0f;  // CLS always kept
}

// ---------------------------------------------------------------------------
// Pass CTX (+score_delta tail blocks): masked renormalized context -> bf16
// in TILED PRE-SWIZZLED layout.  Single-buffered K/V (4 blocks/CU).
// ---------------------------------------------------------------------------
__global__ __launch_bounds__(512) void attn_ctx_mfma(const ushort* __restrict__ qh,
                                                     const ushort* __restrict__ ql,
                                                     const ushort* __restrict__ kh,
                                                     const ushort* __restrict__ vtp,
                                                     const float* __restrict__ kvmask,
                                                     ushort* __restrict__ ctxb,
                                                     float* __restrict__ sd) {
    if (blockIdx.x >= 5 * B_ * H_) {
        int idx = (blockIdx.x - 5 * B_ * H_) * 512 + threadIdx.x;
        if (idx < H_ * N_) {
            int n = idx % N_;
            float d = 0.f;
            if (n != 0) {
#pragma unroll
                for (int b = 0; b < B_; b++) d += kvmask[b * N_ + n];
            }
            sd[idx] = d * (1.0f / (float)B_);
        }
        return;
    }
    __shared__ ushort Kh[4096], Vt[4096];
    __shared__ ushort Pl[2][4096];
    __shared__ float mkAll[640];
    float (*red)[64] = (float(*)[64])&Pl[0][0];
    float* inv = (float*)&Pl[1][0];
    const int bid = xcd_swz(blockIdx.x, 5 * B_ * H_);
    const int bh = bid / 5, q0 = (bid % 5) * 128;
    const int b = bh / H_, h = bh % H_;
    const int tid = threadIdx.x, lane = tid & 63, wv = tid >> 6;
    const int wg = wv >> 2, wl = wv & 3;
    const int lr = lane & 15, ls = lane >> 4;
    const size_t bho = (size_t)bh * PLROW;
    const ushort* qhp = qh + bho; const ushort* qlp = ql + bho;
    const ushort* khp = kh + bho;
    const ushort* vtb = vtp + (size_t)bh * 10 * 4096;
    ushort* PlS = &Pl[0][0];
    for (int i2 = tid; i2 < 640; i2 += 512)
        mkAll[i2] = (i2 < N_) ? kvmask[(size_t)b * N_ + i2] : 0.f;
    auto qrow = [&](int rr) { return (size_t)min(q0 + wv * 16 + rr * 8 + (lane >> 3), N_ - 1) * 64 + (lane & 7) * 8; };
    bf16x8_t fqh[4][2], fql[4][2];
    gload16(qhp + qrow(0), &PlS[wv * 1024]);
    gload16(qhp + qrow(1), &PlS[wv * 1024 + 512]);
    VMCNT(0); __syncthreads();
#pragma unroll
    for (int i = 0; i < 4; i++)
#pragma unroll
        for (int c = 0; c < 2; c++)
            fqh[i][c] = fragT(PlS, wg * 64 + i * 16 + lr, c, ls);
    __syncthreads();
    gload16(qlp + qrow(0), &PlS[wv * 1024]);
    gload16(qlp + qrow(1), &PlS[wv * 1024 + 512]);
    VMCNT(0); __syncthreads();
#pragma unroll
    for (int i = 0; i < 4; i++)
#pragma unroll
        for (int c = 0; c < 2; c++)
            fql[i][c] = fragT(PlS, wg * 64 + i * 16 + lr, c, ls);
    __syncthreads();
    auto krow = [&](int j0) { return (size_t)min(j0 + wv * 8 + (lane >> 3), N_ - 1) * 64 + (lane & 7) * 8; };
    auto stageKV = [&](int t) {
        gload16(khp + krow(t * 64), &Kh[wv * 512]);
        gload16(vtb + (size_t)t * 4096 + wv * 512 + lane * 8, &Vt[wv * 512]);
    };
    float mq[4];
#pragma unroll
    for (int i = 0; i < 4; i++) mq[i] = mkAll[q0 + wg * 64 + i * 16 + lr];
    stageKV(0);
    VMCNT(0);
    SB(); __builtin_amdgcn_s_barrier(); SB();
    f32x4_t acc[4] = {};
    float psums[4] = {0.f, 0.f, 0.f, 0.f};
#pragma unroll 1
    for (int t = 0; t < 10; ++t) {
        bf16x8_t fkh[2], fv[2];
#pragma unroll
        for (int c = 0; c < 2; c++) {
            fkh[c] = fragT(Kh, wl * 16 + lr, c, ls);
            fv[c]  = fragT(Vt, wl * 16 + lr, c, ls);
        }
        LGKM0(); SB();
        __builtin_amdgcn_s_barrier();       // all waves' K/V reads retired
        SB();
        if (t < 9) stageKV(t + 1);          // async overwrite, hidden
        int jloc = wl * 16 + ls * 4;
        float jmv[4], jbias[4];
#pragma unroll
        for (int r = 0; r < 4; r++) {
            int j = t * 64 + jloc + r;
            jmv[r] = mkAll[t * 64 + jloc + r];
            jbias[r] = (j < N_) ? 0.f : -16384.f;
        }
#pragma unroll
        for (int i = 0; i < 4; i++) {
            f32x4_t s = {0.f, 0.f, 0.f, 0.f};
            __builtin_amdgcn_s_setprio(1);
#pragma unroll
            for (int c = 0; c < 2; c++) {
                s = mfma_bf16(fkh[c], fqh[i][c], s);
                s = mfma_bf16(fkh[c], fql[i][c], s);
            }
            __builtin_amdgcn_s_setprio(0);
            bf16x4_t pb;
            float mqi = mq[i];
#pragma unroll
            for (int r = 0; r < 4; r++) {
                float p = __builtin_amdgcn_exp2f(s[r] + jbias[r]) * fmaxf(mqi, jmv[r]);
                psums[i] += p;
                pb[r] = (__bf16)p;
            }
            int row = i * 16 + lr;
            int slot = ((wl << 1) + (ls >> 1)) ^ (row & 7);
            *(u32x2_t*)&Pl[wg][(row << 6) + (slot << 3) + ((ls & 1) << 2)] =
                __builtin_bit_cast(u32x2_t, pb);
        }
        SB(); LGKM0(); SB();
        __builtin_amdgcn_s_barrier();       // P visible, vmcnt untouched
        SB();
        __builtin_amdgcn_s_setprio(1);
#pragma unroll
        for (int i = 0; i < 4; i++) {
            bf16x8_t fp0 = fragT(Pl[wg], i * 16 + lr, 0, ls);
            bf16x8_t fp1 = fragT(Pl[wg], i * 16 + lr, 1, ls);
            acc[i] = mfma_bf16(fv[0], fp0, acc[i]);
            acc[i] = mfma_bf16(fv[1], fp1, acc[i]);
        }
        __builtin_amdgcn_s_setprio(0);
        if (t < 9) {
            VMCNT(0); SB();
            __builtin_amdgcn_s_barrier();   // new K/V ready
            SB();
        }
    }
    __syncthreads();
#pragma unroll
    for (int i = 0; i < 4; i++) {
        float v2 = psums[i];
        v2 += __shfl_xor(v2, 16);
        v2 += __shfl_xor(v2, 32);
        if (ls == 0) red[wv][i * 16 + lr] = v2;
    }
    __syncthreads();
    if (tid < 128) {
        int grp = tid >> 6, qlc = tid & 63;
        float t2 = red[grp * 4 + 0][qlc] + red[grp * 4 + 1][qlc] +
                   red[grp * 4 + 2][qlc] + red[grp * 4 + 3][qlc];
        inv[tid] = 1.0f / (t2 + 1e-8f);
    }
    __syncthreads();
#pragma unroll
    for (int i = 0; i < 4; i++) {
        int qn = q0 + wg * 64 + i * 16 + lr;
        if (qn < N_) {
            float rn = inv[wg * 64 + i * 16 + lr];
            bf16x4_t ov;
            ov[0] = (__bf16)(acc[i][0] * rn);
            ov[1] = (__bf16)(acc[i][1] * rn);
            ov[2] = (__bf16)(acc[i][2] * rn);
            ov[3] = (__bf16)(acc[i][3] * rn);
            int m = b * N_ + qn;
            int col = h * D_ + wl * 16 + ls * 4;
            int mt = m >> 7, rowl = m & 127;
            int kt2 = col >> 5, c32 = col & 31;
            int phys = (c32 >> 3) ^ ((rowl >> 1) & 3);
            size_t off = ((size_t)(mt * NKT + kt2)) * 4096 + rowl * 32 + phys * 8 + (c32 & 7);
            *(u32x2_t*)&ctxb[off] = __builtin_bit_cast(u32x2_t, ov);
        }
    }
}

// ---------------------------------------------------------------------------
// MFMA GEMM 2 (plain bf16, tiled pre-swizzled A and B): counted-vmcnt pipeline
// out = context_bf16 @ Wproj^T + bproj
// ---------------------------------------------------------------------------
__global__ __launch_bounds__(256) void gemm_proj_mfma(const ushort* __restrict__ Apl,
                                                      const ushort* __restrict__ Bpl,
                                                      const float* __restrict__ bias,
                                                      float* __restrict__ out) {
    __shared__ ushort Ab[2][4096], Bb[2][4096];
    const int bid = xcd_swz(blockIdx.x, 6 * 73);
    const int bx = bid % 6, by = bid / 6;
    const int tid = threadIdx.x;
    const int lane = tid & 63, wave = tid >> 6;
    const int wr = wave >> 1, wc = wave & 1;
    const int lr = lane & 15, ls = lane >> 4;
    const int m0 = by * 128, n0 = bx * 128;
    const int o0 = wave * 1024, o1 = o0 + 512;
    const int la = lane * 8;
    const size_t abase = (size_t)by * NKT * 4096;
    const size_t bbase = (size_t)bx * NKT * 4096;
    f32x4_t acc[4][4] = {};

    auto stage = [&](int buf, int kt) {
        const size_t ta = abase + (size_t)kt * 4096;
        const size_t tb = bbase + (size_t)kt * 4096;
        gload16(Apl + ta + o0 + la, &Ab[buf][o0]);
        gload16(Apl + ta + o1 + la, &Ab[buf][o1]);
        gload16(Bpl + tb + o0 + la, &Bb[buf][o0]);
        gload16(Bpl + tb + o1 + la, &Bb[buf][o1]);
    };
    stage(0, 0);
#pragma unroll 1
    for (int kt = 0; kt < NKT; ++kt) {
        const int cur = kt & 1;
        if (kt + 1 < NKT) {
            stage(cur ^ 1, kt + 1);
            VMCNT(4);
        } else {
            VMCNT(0);
        }
        SB();
        __builtin_amdgcn_s_barrier();
        SB();
        bf16x8_t fa[4], fb[4];
#pragma unroll
        for (int i = 0; i < 4; i++) {
            int rowA = wr * 64 + i * 16 + lr;
            int pa = ls ^ ((rowA >> 1) & 3);
            fa[i] = __builtin_bit_cast(bf16x8_t, *(const u32x4_t*)&Ab[cur][rowA * 32 + pa * 8]);
            int rowB = wc * 64 + i * 16 + lr;
            int pb = ls ^ ((rowB >> 1) & 3);
            fb[i] = __builtin_bit_cast(bf16x8_t, *(const u32x4_t*)&Bb[cur][rowB * 32 + pb * 8]);
        }
#pragma unroll
        for (int i = 0; i < 4; i++)
#pragma unroll
            for (int j = 0; j < 4; j++)
                acc[i][j] = mfma_bf16(fa[i], fb[j], acc[i][j]);
        if (kt + 1 < NKT) {
            SB();
            __builtin_amdgcn_s_barrier();
        }
    }
#pragma unroll
    for (int j = 0; j < 4; j++) {
        int ng = n0 + wc * 64 + j * 16 + lr;
        float bb = bias[ng];
#pragma unroll
        for (int i = 0; i < 4; i++) {
            int mg0 = m0 + wr * 64 + i * 16 + ls * 4;
#pragma unroll
            for (int r = 0; r < 4; r++) {
                int m = mg0 + r;
                if (m < M_TOT) out[(size_t)m * C_ + ng] = acc[i][j][r] + bb;
            }
        }
    }
}

// ---------------------------------------------------------------------------
extern "C" void kernel_launch(void* const* d_in, const int* in_sizes, int n_in,
                              void* d_out, int out_size, void* d_ws, size_t ws_size,
                              hipStream_t stream) {
    const float* x     = (const float*)d_in[0];
    const float* ucb   = (const float*)d_in[1];
    const float* Wqkv  = (const float*)d_in[2];
    const float* Wproj = (const float*)d_in[3];
    const float* bproj = (const float*)d_in[4];
    const int*   counter = (const int*)d_in[5];

    const size_t BHN  = (size_t)B_ * H_ * N_;       // 110,784
    const size_t XPL  = (size_t)(73 * 128) * C_;    // 7,176,192
    const size_t WPL  = (size_t)3 * C_ * C_;        // 1,769,472
    const size_t WPJ  = (size_t)C_ * C_;            // 589,824 (= 144 tiles)
    const size_t PLN  = (size_t)192 * PLROW;        // 7,090,176 ushorts per plane
    const size_t VTSZ = (size_t)192 * 10 * 4096;    // 7,864,320 ushorts

    ushort* qhp  = (ushort*)d_ws;
    ushort* qlp  = qhp + PLN;
    ushort* khp  = qlp + PLN;
    ushort* klp  = khp + PLN;
    ushort* vtp  = klp + PLN;
    ushort* XplH = vtp + VTSZ;
    ushort* XplL = XplH + XPL;
    ushort* ctxb = XplH;                 // alias: X planes dead after gemm_qkv
    ushort* WplH = XplL + XPL;
    ushort* WplL = WplH + WPL;
    ushort* Wpjb = WplL + WPL;
    float*  w    = (float*)(Wpjb + WPJ);
    float*  colsum = w + BHN;
    float*  kvmask = colsum + BHN;
    size_t need = ((char*)(kvmask + (size_t)B_ * N_)) - (char*)d_ws;
    if (ws_size < need) {
        fprintf(stderr, "kernel_launch: ws too small, need %zu have %zu\n",
                need, ws_size);
        return;
    }

    float* out  = (float*)d_out;
    float* sd   = out + (size_t)B_ * N_ * C_;
    float* kept = sd + (size_t)H_ * N_;

    pack_all_kernel<<<NXP + NWP + NPJ + NZ, 256, 0, stream>>>(
        x, Wqkv, Wproj, XplH, XplL, WplH, WplL, Wpjb, kvmask);

    gemm_qkv_mfma<<<18 * 73, 256, 0, stream>>>(XplH, XplL, WplH, WplL,
                                               qhp, qlp, khp, klp, vtp);
    attn_rowsum_mfma<<<5 * B_ * H_, 512, 0, stream>>>(qhp, qlp, khp, klp, w);
    attn_colsum_mfma<<<5 * B_ * H_, 512, 0, stream>>>(qhp, qlp, khp, klp, w, colsum);
    topk_kernel<<<B_, 512, 0, stream>>>(colsum, ucb, counter, kept, kvmask);
    attn_ctx_mfma<<<5 * B_ * H_ + 14, 512, 0, stream>>>(qhp, qlp, khp, vtp,
                                                        kvmask, ctxb, sd);
    gemm_proj_mfma<<<6 * 73, 256, 0, stream>>>(ctxb, Wpjb, bproj, out);
}